// Round 1
// baseline (117.824 us; speedup 1.0000x reference)
//
#include <hip/hip_runtime.h>

// Problem constants (from reference)
#define NPTS   4096
#define NEVT   1000000
#define TILE   64
#define NT     (NPTS / TILE)                 // 64 tiles per dim
#define PAIR_BLOCKS (NT * (NT + 1) / 2)      // 2080 upper-tri tile blocks
#define BLK    256
#define EVT_PER_THREAD 4
#define EVT_BLOCKS ((NEVT + BLK * EVT_PER_THREAD - 1) / (BLK * EVT_PER_THREAD)) // 977

// Abramowitz-Stegun 7.1.26: |err| <= 1.5e-7, one exp + one rcp
__device__ __forceinline__ float fast_erff(float x) {
    float ax = __builtin_fabsf(x);
    float t  = __builtin_amdgcn_rcpf(__builtin_fmaf(0.3275911f, ax, 1.0f));
    float p  = __builtin_fmaf(t, 1.061405429f, -1.453152027f);
    p = __builtin_fmaf(t, p, 1.421413741f);
    p = __builtin_fmaf(t, p, -0.284496736f);
    p = __builtin_fmaf(t, p, 0.254829592f);
    p = p * t;
    float e = __builtin_amdgcn_exp2f(-ax * ax * 1.4426950408889634f);
    float r = __builtin_fmaf(-p, e, 1.0f);
    return __builtin_copysignf(r, x);
}

__global__ __launch_bounds__(BLK) void hawkes_fused_kernel(
    const float* __restrict__ z0, const float* __restrict__ v0,
    const float* __restrict__ et, const float* __restrict__ t0p,
    const float* __restrict__ tnp, const int* __restrict__ uix,
    const int* __restrict__ vix, float* __restrict__ out)
{
    __shared__ float4 tileJ[TILE];
    __shared__ float  red[BLK / 64];
    const int tid = threadIdx.x;
    const float2* z2 = (const float2*)z0;
    const float2* v2 = (const float2*)v0;

    float contrib = 0.0f;

    if (blockIdx.x < PAIR_BLOCKS) {
        // ---- non-event (pair) term: tile (bi, bj), bi <= bj over upper triangle
        const float t0 = *t0p;
        const float tn = *tnp;
        int L  = (int)blockIdx.x;
        // invert triangular row offset: O(bi) = bi*NT - bi*(bi-1)/2
        int bi = (int)((129.0f - sqrtf((float)(16641 - 8 * L))) * 0.5f);
        while (bi * NT - bi * (bi - 1) / 2 > L) --bi;
        while ((bi + 1) * NT - (bi + 1) * bi / 2 <= L) ++bi;
        int bj = bi + (L - (bi * NT - bi * (bi - 1) / 2));

        // stage j-tile into LDS (16 B per point)
        if (tid < TILE) {
            int j = bj * TILE + tid;
            float2 zj = z2[j], vj = v2[j];
            tileJ[tid] = make_float4(zj.x, zj.y, vj.x, vj.y);
        }
        __syncthreads();

        const int il = tid & 63;
        const int i  = bi * TILE + il;
        const float2 zi = z2[i];
        const float2 vi = v2[i];
        const int jw = tid >> 6;  // wave id 0..3: each wave owns 16 contiguous j's

        float acc = 0.0f;
        #pragma unroll
        for (int k = 0; k < 16; ++k) {
            int jl = jw * 16 + k;          // wave-uniform -> LDS broadcast read
            int j  = bj * TILE + jl;
            if (j > i) {                   // always true on off-diagonal tiles
                float4 tj = tileJ[jl];
                float a = zi.x - tj.x;
                float b = zi.y - tj.y;
                float m = vi.x - tj.z;
                float n = vi.y - tj.w;
                float mn2   = __builtin_fmaf(m, m, n * n);
                float cross = __builtin_fmaf(a, n, -b * m);
                float dot   = __builtin_fmaf(a, m, b * n);
                float rmn2  = __builtin_amdgcn_rcpf(mn2);
                // alpha = beta = 1: exponent = 1 - cross^2 / mn2
                float ex    = __builtin_fmaf(-cross * cross, rmn2, 1.0f);
                float expo  = __builtin_amdgcn_exp2f(ex * 1.4426950408889634f);
                float invs  = __builtin_amdgcn_rsqf(mn2);   // 1/sqrt(mn2)
                float arg0  = __builtin_fmaf(mn2, t0, dot) * invs;
                float arg1  = __builtin_fmaf(mn2, tn, dot) * invs;
                float df    = fast_erff(arg1) - fast_erff(arg0);
                acc = __builtin_fmaf(df * expo, invs, acc);
            }
        }
        // integral = sqrt(pi)/2 * expo * (erf1-erf0) * invs; output subtracts it
        contrib = -0.8862269254527580f * acc;
    } else {
        // ---- event term: sum_e (beta - ||dz0 + dv0*t||^2)
        int gid  = ((int)blockIdx.x - PAIR_BLOCKS) * BLK + tid;
        int base = gid * EVT_PER_THREAD;
        float acc = 0.0f;
        if (base + EVT_PER_THREAD <= NEVT) {
            float4 t4 = *(const float4*)(et + base);
            int4   u4 = *(const int4*)(uix + base);
            int4   v4 = *(const int4*)(vix + base);
            float tt[4] = {t4.x, t4.y, t4.z, t4.w};
            int   uu[4] = {u4.x, u4.y, u4.z, u4.w};
            int   vv[4] = {v4.x, v4.y, v4.z, v4.w};
            #pragma unroll
            for (int e = 0; e < 4; ++e) {
                float2 zu = z2[uu[e]], zv = z2[vv[e]];
                float2 pu = v2[uu[e]], pv = v2[vv[e]];
                float dx = __builtin_fmaf(pu.x - pv.x, tt[e], zu.x - zv.x);
                float dy = __builtin_fmaf(pu.y - pv.y, tt[e], zu.y - zv.y);
                acc += 1.0f - (dx * dx + dy * dy);   // beta = 1
            }
        } else {
            for (int e = base; e < NEVT; ++e) {
                float te = et[e];
                int u = uix[e], v = vix[e];
                float2 zu = z2[u], zv = z2[v];
                float2 pu = v2[u], pv = v2[v];
                float dx = __builtin_fmaf(pu.x - pv.x, te, zu.x - zv.x);
                float dy = __builtin_fmaf(pu.y - pv.y, te, zu.y - zv.y);
                acc += 1.0f - (dx * dx + dy * dy);
            }
        }
        contrib = acc;
    }

    // ---- block reduction: wave shuffle -> LDS -> single atomic per block
    #pragma unroll
    for (int off = 32; off > 0; off >>= 1)
        contrib += __shfl_down(contrib, off, 64);
    if ((tid & 63) == 0) red[tid >> 6] = contrib;
    __syncthreads();
    if (tid == 0) {
        float s = red[0] + red[1] + red[2] + red[3];
        atomicAdd(out, s);
    }
}

extern "C" void kernel_launch(void* const* d_in, const int* in_sizes, int n_in,
                              void* d_out, int out_size, void* d_ws, size_t ws_size,
                              hipStream_t stream) {
    const float* z0  = (const float*)d_in[0];
    const float* v0  = (const float*)d_in[1];
    const float* et  = (const float*)d_in[2];
    const float* t0p = (const float*)d_in[3];
    const float* tnp = (const float*)d_in[4];
    const int*   uix = (const int*)d_in[5];
    const int*   vix = (const int*)d_in[6];
    float* out = (float*)d_out;

    hipMemsetAsync(out, 0, sizeof(float), stream);
    int grid = PAIR_BLOCKS + EVT_BLOCKS;
    hipLaunchKernelGGL(hawkes_fused_kernel, dim3(grid), dim3(BLK), 0, stream,
                       z0, v0, et, t0p, tnp, uix, vix, out);
}

// Round 2
// 111.782 us; speedup vs baseline: 1.0540x; 1.0540x over previous
//
#include <hip/hip_runtime.h>

// Problem constants (from reference)
#define NPTS   4096
#define NEVT   1000000
#define NQUAD  (NEVT / 4)                    // 250000, exact
#define TILE   64
#define NT     (NPTS / TILE)                 // 64 tiles per dim
#define PAIR_BLOCKS (NT * (NT + 1) / 2)      // 2080 upper-tri tile blocks
#define BLK    256
#define EVT_BLOCKS 512

// Abramowitz-Stegun 7.1.26: |err| <= 1.5e-7, one exp + one rcp
__device__ __forceinline__ float fast_erff(float x) {
    float ax = __builtin_fabsf(x);
    float t  = __builtin_amdgcn_rcpf(__builtin_fmaf(0.3275911f, ax, 1.0f));
    float p  = __builtin_fmaf(t, 1.061405429f, -1.453152027f);
    p = __builtin_fmaf(t, p, 1.421413741f);
    p = __builtin_fmaf(t, p, -0.284496736f);
    p = __builtin_fmaf(t, p, 0.254829592f);
    p = p * t;
    float e = __builtin_amdgcn_exp2f(-ax * ax * 1.4426950408889634f);
    float r = __builtin_fmaf(-p, e, 1.0f);
    return __builtin_copysignf(r, x);
}

__global__ __launch_bounds__(BLK) void hawkes_fused_kernel(
    const float* __restrict__ z0, const float* __restrict__ v0,
    const float* __restrict__ et, const float* __restrict__ t0p,
    const float* __restrict__ tnp, const int* __restrict__ uix,
    const int* __restrict__ vix, float* __restrict__ out)
{
    // 64 KB: full packed point table for event blocks; pair blocks use [0..63]
    __shared__ float4 pts[NPTS];
    __shared__ float  red[BLK / 64];
    const int tid = threadIdx.x;
    const float2* z2 = (const float2*)z0;
    const float2* v2 = (const float2*)v0;

    float contrib = 0.0f;

    if (blockIdx.x < EVT_BLOCKS) {
        // ---- event term: sum_e (beta - ||dz0 + dv0*t||^2) with LDS-staged table
        #pragma unroll
        for (int k = 0; k < NPTS / BLK; ++k) {
            int p = tid + k * BLK;
            float2 zp = z2[p], vp = v2[p];
            pts[p] = make_float4(zp.x, zp.y, vp.x, vp.y);
        }
        __syncthreads();

        const int stride = EVT_BLOCKS * BLK;
        float acc = 0.0f;
        for (int q = (int)blockIdx.x * BLK + tid; q < NQUAD; q += stride) {
            int base = q * 4;
            float4 t4 = *(const float4*)(et + base);
            int4   u4 = *(const int4*)(uix + base);
            int4   v4 = *(const int4*)(vix + base);
            float tt[4] = {t4.x, t4.y, t4.z, t4.w};
            int   uu[4] = {u4.x, u4.y, u4.z, u4.w};
            int   vv[4] = {v4.x, v4.y, v4.z, v4.w};
            #pragma unroll
            for (int e = 0; e < 4; ++e) {
                float4 P = pts[uu[e]];
                float4 Q = pts[vv[e]];
                float dx = __builtin_fmaf(P.z - Q.z, tt[e], P.x - Q.x);
                float dy = __builtin_fmaf(P.w - Q.w, tt[e], P.y - Q.y);
                acc += 1.0f - (dx * dx + dy * dy);   // beta = 1
            }
        }
        contrib = acc;
    } else {
        // ---- non-event (pair) term: tile (bi, bj), bi <= bj over upper triangle
        const float t0 = *t0p;
        const float tn = *tnp;
        int L  = (int)blockIdx.x - EVT_BLOCKS;
        // invert triangular row offset: O(bi) = bi*NT - bi*(bi-1)/2
        int bi = (int)((129.0f - sqrtf((float)(16641 - 8 * L))) * 0.5f);
        while (bi * NT - bi * (bi - 1) / 2 > L) --bi;
        while ((bi + 1) * NT - (bi + 1) * bi / 2 <= L) ++bi;
        int bj = bi + (L - (bi * NT - bi * (bi - 1) / 2));

        // stage j-tile into LDS (16 B per point)
        if (tid < TILE) {
            int j = bj * TILE + tid;
            float2 zj = z2[j], vj = v2[j];
            pts[tid] = make_float4(zj.x, zj.y, vj.x, vj.y);
        }
        __syncthreads();

        const int il = tid & 63;
        const int i  = bi * TILE + il;
        const float2 zi = z2[i];
        const float2 vi = v2[i];
        const int jw = tid >> 6;  // wave id 0..3: each wave owns 16 contiguous j's

        float acc = 0.0f;
        #pragma unroll
        for (int k = 0; k < 16; ++k) {
            int jl = jw * 16 + k;          // wave-uniform -> LDS broadcast read
            int j  = bj * TILE + jl;
            if (j > i) {                   // always true on off-diagonal tiles
                float4 tj = pts[jl];
                float a = zi.x - tj.x;
                float b = zi.y - tj.y;
                float m = vi.x - tj.z;
                float n = vi.y - tj.w;
                float mn2   = __builtin_fmaf(m, m, n * n);
                float cross = __builtin_fmaf(a, n, -b * m);
                float dot   = __builtin_fmaf(a, m, b * n);
                float rmn2  = __builtin_amdgcn_rcpf(mn2);
                // alpha = beta = 1: exponent = 1 - cross^2 / mn2
                float ex    = __builtin_fmaf(-cross * cross, rmn2, 1.0f);
                float expo  = __builtin_amdgcn_exp2f(ex * 1.4426950408889634f);
                float invs  = __builtin_amdgcn_rsqf(mn2);   // 1/sqrt(mn2)
                float arg0  = __builtin_fmaf(mn2, t0, dot) * invs;
                float arg1  = __builtin_fmaf(mn2, tn, dot) * invs;
                float df    = fast_erff(arg1) - fast_erff(arg0);
                acc = __builtin_fmaf(df * expo, invs, acc);
            }
        }
        // integral = sqrt(pi)/2 * expo * (erf1-erf0) * invs; output subtracts it
        contrib = -0.8862269254527580f * acc;
    }

    // ---- block reduction: wave shuffle -> LDS -> single atomic per block
    #pragma unroll
    for (int off = 32; off > 0; off >>= 1)
        contrib += __shfl_down(contrib, off, 64);
    if ((tid & 63) == 0) red[tid >> 6] = contrib;
    __syncthreads();
    if (tid == 0) {
        float s = red[0] + red[1] + red[2] + red[3];
        atomicAdd(out, s);
    }
}

extern "C" void kernel_launch(void* const* d_in, const int* in_sizes, int n_in,
                              void* d_out, int out_size, void* d_ws, size_t ws_size,
                              hipStream_t stream) {
    const float* z0  = (const float*)d_in[0];
    const float* v0  = (const float*)d_in[1];
    const float* et  = (const float*)d_in[2];
    const float* t0p = (const float*)d_in[3];
    const float* tnp = (const float*)d_in[4];
    const int*   uix = (const int*)d_in[5];
    const int*   vix = (const int*)d_in[6];
    float* out = (float*)d_out;

    hipMemsetAsync(out, 0, sizeof(float), stream);
    int grid = EVT_BLOCKS + PAIR_BLOCKS;
    hipLaunchKernelGGL(hawkes_fused_kernel, dim3(grid), dim3(BLK), 0, stream,
                       z0, v0, et, t0p, tnp, uix, vix, out);
}